// Round 7
// baseline (982.864 us; speedup 1.0000x reference)
//
#include <hip/hip_runtime.h>
#include <hip/hip_bf16.h>
#include <math.h>

typedef short bf16x8 __attribute__((ext_vector_type(8)));
typedef float f32x4 __attribute__((ext_vector_type(4)));
typedef __hip_bfloat16 bf16;

#define NEGV -1e10f
#define LOGEPS -9.210340371976182f  // log(1e-4)
#define HL2PI 0.9189385332046727f   // 0.5*log(2*pi)
#define SENT 0xFFFFFFFFFFFFFFFFULL

__device__ __forceinline__ f32x4 mfma16(bf16x8 a, bf16x8 b, f32x4 c) {
  return __builtin_amdgcn_mfma_f32_16x16x32_bf16(a, b, c, 0, 0, 0);
}
__device__ __forceinline__ bf16x8 ld8(const bf16* p) { return *(const bf16x8*)(const void*)p; }
__device__ __forceinline__ bf16 f2b(float v) { return __float2bfloat16(v); }
__device__ __forceinline__ float sh2f(short s) {
  unsigned u = ((unsigned)(unsigned short)s) << 16; float f; __builtin_memcpy(&f, &u, 4); return f;
}
__device__ __forceinline__ short f2sh(float v) {
  bf16 b = f2b(v); short s; __builtin_memcpy(&s, &b, 2); return s;
}
__device__ __forceinline__ float fsigm(float x) { return 1.f / (1.f + __expf(-x)); }
__device__ __forceinline__ float ftanh(float x) { return 1.f - 2.f / (1.f + __expf(2.f * x)); }
__device__ __forceinline__ unsigned long long AL64(const unsigned long long* p) {
  return __hip_atomic_load(p, __ATOMIC_RELAXED, __HIP_MEMORY_SCOPE_AGENT);
}
__device__ __forceinline__ void AS64(unsigned long long* p, unsigned long long v) {
  __hip_atomic_store(p, v, __ATOMIC_RELAXED, __HIP_MEMORY_SCOPE_AGENT);
}
__device__ __forceinline__ int AL32(const int* p) {
  return __hip_atomic_load(p, __ATOMIC_RELAXED, __HIP_MEMORY_SCOPE_AGENT);
}
__device__ __forceinline__ void AS32(int* p, int v) {
  __hip_atomic_store(p, v, __ATOMIC_RELAXED, __HIP_MEMORY_SCOPE_AGENT);
}
__device__ __forceinline__ bf16x8 frag2(unsigned long long a, unsigned long long b) {
  union { unsigned long long u[2]; bf16x8 f; } cv; cv.u[0] = a; cv.u[1] = b; return cv.f;
}

// ---------------------------------------------------------------- prep
__global__ void k_prep(const float* __restrict__ inputs, const float* __restrict__ mels,
                       const float* __restrict__ pw0, const float* __restrict__ pw1,
                       const float* __restrict__ wih, const float* __restrict__ whh,
                       const float* __restrict__ bih, const float* __restrict__ bhh,
                       const float* __restrict__ ow0, const float* __restrict__ ow1,
                       const float* __restrict__ ow2, const float* __restrict__ ob2,
                       bf16* ib, bf16* ar, bf16* w0p, bf16* w1b, bf16* wihb, bf16* whhb,
                       float* bias2, bf16* ow0Eb, bf16* ow0Mb, bf16* ow1b, bf16* ow2pb,
                       float* ob2p, unsigned long long* hg, int* emi, int* tvi, int* prog) {
  int t0 = blockIdx.x * blockDim.x + threadIdx.x;
  int nt = gridDim.x * blockDim.x;
  for (int i = t0; i < 256 * 1024; i += nt) hg[i] = SENT;   // data-poll sentinels
  for (int i = t0; i < 2048 * 128; i += nt) { emi[i] = -1; tvi[i] = -1; }
  for (int i = t0; i < 256; i += nt) prog[i] = 0;
  for (int i = t0; i < 8*128*512; i += nt) ib[i] = f2b(inputs[i]);
  for (int i = t0; i < 2048*96; i += nt) {
    int r = i / 96, d = i - r * 96; int t = r >> 3, b = r & 7;
    float v = (d < 80 && t > 0) ? mels[((size_t)b*80 + d)*256 + (t-1)] : 0.f;
    ar[i] = f2b(v);
  }
  for (int i = t0; i < 256*96; i += nt) {
    int j = i / 96, d = i - j * 96;
    w0p[i] = f2b(d < 80 ? pw0[j*80 + d] : 0.f);
  }
  for (int i = t0; i < 256*256; i += nt) w1b[i] = f2b(pw1[i]);
  for (int i = t0; i < 2048*256; i += nt) wihb[i] = f2b(wih[i]);
  for (int i = t0; i < 2048*512; i += nt) whhb[i] = f2b(whh[i]);
  for (int i = t0; i < 2048; i += nt) bias2[i] = bih[i] + bhh[i];
  for (int i = t0; i < 256*512; i += nt) {
    int j = i >> 9, k = i & 511;
    ow0Eb[i] = f2b(ow0[(size_t)j*1024 + k]);
    ow0Mb[i] = f2b(ow0[(size_t)j*1024 + 512 + k]);
  }
  for (int i = t0; i < 256*256; i += nt) ow1b[i] = f2b(ow1[i]);
  for (int i = t0; i < 176*256; i += nt) {
    int r = i >> 8;
    ow2pb[i] = f2b(r < 161 ? ow2[i] : 0.f);
  }
  for (int i = t0; i < 176; i += nt) ob2p[i] = (i < 161) ? ob2[i] : 0.f;
}

// ---------------------------------------------------------------- generic MFMA GEMM (head stages)
__global__ __launch_bounds__(256) void k_gemm(const bf16* __restrict__ A, const bf16* __restrict__ W,
                                              const float* __restrict__ bias, void* __restrict__ Cout,
                                              int M, int N, int K, int flags) {
  int wave = threadIdx.x >> 6, lane = threadIdx.x & 63;
  int l16 = lane & 15, quad = lane >> 4;
  int row0 = blockIdx.y * 64 + wave * 16;
  int col0 = blockIdx.x * 64;
  const bf16* arow = A + (size_t)(row0 + l16) * K + quad * 8;
  f32x4 acc[4] = {};
  for (int kt = 0; kt < K; kt += 32) {
    bf16x8 af = ld8(arow + kt);
#pragma unroll
    for (int nt = 0; nt < 4; nt++) {
      bf16x8 wf = ld8(W + (size_t)(col0 + nt*16 + l16) * K + kt + quad * 8);
      acc[nt] = mfma16(af, wf, acc[nt]);
    }
  }
#pragma unroll
  for (int nt = 0; nt < 4; nt++) {
    int col = col0 + nt * 16 + l16;
    float bv = bias ? bias[col] : 0.f;
#pragma unroll
    for (int r = 0; r < 4; r++) {
      int row = row0 + quad * 4 + r;
      float v = acc[nt][r] + bv;
      if (flags & 1) v = v > 0.f ? v : 0.f;
      if (flags & 2) ((bf16*)Cout)[(size_t)row * N + col] = f2b(v);
      else ((float*)Cout)[(size_t)row * N + col] = v;
    }
  }
}

// ---------------------------------------------------------------- mega kernel v3
// EXACTLY 256 blocks x 256 thr; LDS padded to ~85KB > 160KiB/2 so the HW allows
// only 1 block/CU -> every block owns a dedicated CU, all 256 co-resident by
// capacity (no dispatch-order assumption). The lstm scan runs on 32 private CUs
// with zero co-resident interference (R6's 2x slowdown + retry storm fix).
//   [0,8)    hmm-role : per-batch HMM forward, polls em/tv sentinels (paced)
//   [8,40)   lstm-role: v4 engine, 4 waves x 4 units; block polls h into LDS
//   [40,256) out-role : handles t = bid-40 and t+216 (if <256); spins one word
//                       (prog[t]), one-shot sentinel-verified hg read,
//                       hterm MFMA + outnet + emission, publish em/tv
#define LDA1 264
__global__ __launch_bounds__(256, 1) void k_mega(
    const float* __restrict__ gx, const bf16* __restrict__ whhb,
    unsigned long long* __restrict__ hg, const bf16* __restrict__ ow0Mb,
    const bf16* __restrict__ baseb, const bf16* __restrict__ w1,
    const bf16* __restrict__ w2, const float* __restrict__ ob1,
    const float* __restrict__ ob2p, const float* __restrict__ mels,
    const int* __restrict__ ilen, const int* __restrict__ mlen,
    int* __restrict__ emi, int* __restrict__ tvi, int* __restrict__ prog,
    float* __restrict__ out) {
  // 128*264*2 + 4096*2 = 75776 B; + ht2 8192 + xt 320 + ob2s 704 = 84992 B > 81920
  __shared__ __align__(16) bf16 a_buf[128 * LDA1 + 4096];
  __shared__ float ht2[8 * 256];
  __shared__ float xt[80];
  __shared__ float ob2s[176];
  const int bid = blockIdx.x, tid = threadIdx.x;
  const int wave = tid >> 6, lane = tid & 63, l16 = lane & 15, quad = lane >> 4;
  if (tid == 0) a_buf[128 * LDA1 + (bid & 4095)] = f2b(0.f);  // keep pad alive

  if (bid < 8) {  // ================= HMM role =================
    if (tid >= 64) return;
    const int b = bid, ln = tid;
    const int len = ilen[b], ml = mlen[b];
    const bool m0 = ln < len, m1 = (64 + ln) < len;
    float la0 = 0.f, la1 = 0.f, lp = 0.f;
    for (int t = 0; t < 256; t++) {
      const size_t idx = (size_t)t * 1024 + b * 128 + ln;
      int ia0 = AL32(emi + idx), ia1 = AL32(emi + idx + 64);
      int ib0 = AL32(tvi + idx), ib1 = AL32(tvi + idx + 64);
      while (ia0 == -1 || ia1 == -1 || ib0 == -1 || ib1 == -1) {
        __builtin_amdgcn_s_sleep(8);
        if (ia0 == -1) ia0 = AL32(emi + idx);
        if (ia1 == -1) ia1 = AL32(emi + idx + 64);
        if (ib0 == -1) ib0 = AL32(tvi + idx);
        if (ib1 == -1) ib1 = AL32(tvi + idx + 64);
      }
      float e0 = __int_as_float(ia0), e1 = __int_as_float(ia1);
      float v0 = __int_as_float(ib0), v1 = __int_as_float(ib1);
      if (t == 0) {
        la0 = (ln == 0 ? 0.f : NEGV) + e0;
        la1 = NEGV + e1;
      } else {
        float L0 = __logf(1.f + __expf(-fabsf(v0))), L1 = __logf(1.f + __expf(-fabsf(v1)));
        float ls0 = fmaxf(-(fmaxf(v0, 0.f) + L0), LOGEPS);
        float lm0 = fmaxf(-(fmaxf(-v0, 0.f) + L0), LOGEPS);
        float ls1 = fmaxf(-(fmaxf(v1, 0.f) + L1), LOGEPS);
        float lm1 = fmaxf(-(fmaxf(-v1, 0.f) + L1), LOGEPS);
        float stay0 = la0 + ls0, stay1 = la1 + ls1;
        float mv0 = la0 + lm0, mv1 = la1 + lm1;
        float pm0 = __shfl_up(mv0, 1);
        float pm1 = __shfl_up(mv1, 1);
        float mv0_63 = __shfl(mv0, 63);
        float le0 = (ln == 0) ? NEGV : pm0;
        float le1 = (ln == 0) ? mv0_63 : pm1;
        float mxa = fmaxf(stay0, le0), mna = fminf(stay0, le0);
        float o0 = mxa + __logf(1.f + __expf(mna - mxa));
        float mxb = fmaxf(stay1, le1), mnb = fminf(stay1, le1);
        float o1 = mxb + __logf(1.f + __expf(mnb - mxb));
        o0 = m0 ? o0 : NEGV; o1 = m1 ? o1 : NEGV;
        la0 = e0 + o0; la1 = e1 + o1;
      }
      float mx = fmaxf(la0, la1);
#pragma unroll
      for (int s = 1; s < 64; s <<= 1) mx = fmaxf(mx, __shfl_xor(mx, s));
      float sm = __expf(la0 - mx) + __expf(la1 - mx);
#pragma unroll
      for (int s = 1; s < 64; s <<= 1) sm += __shfl_xor(sm, s);
      float lc = mx + __logf(sm);
      la0 -= lc; la1 -= lc;
      size_t o = 8 + ((size_t)b * 256 + t) * 128 + ln;
      out[o] = la0;
      out[o + 64] = la1;
      if (t < ml) lp += lc;
    }
    if (ln == 0) out[b] = lp;
    return;
  }

  if (bid < 40) {  // ================= LSTM role (32 blocks x 4 waves, private CUs) =================
    bf16* hb = a_buf;  // alias: [2][8192] bf16, fragment-order [c4][batch16][8]
    const int q = bid - 8;  // 0..31, owns units q*16 .. q*16+15
    const int jrow = (l16 & 3) * 512 + q * 16 + wave * 4 + (l16 >> 2);
    bf16x8 Af[16];
#pragma unroll
    for (int c = 0; c < 16; c++) Af[c] = ld8(whhb + (size_t)jrow * 512 + c * 32 + quad * 8);
    {
      bf16 z = f2b(0.f);
      for (int i = tid; i < 2 * 8192; i += 256) hb[i] = z;
    }
    const int b_ep = l16 & 7;
    const int gx_col = q * 16 + wave * 4 + quad;
    int wi[4], offs[4];
#pragma unroll
    for (int r = 0; r < 4; r++) {
      wi[r] = tid + 256 * r;
      offs[r] = (((wi[r] & 127) >> 1) * 16 + (wi[r] >> 7)) * 8 + ((wi[r] & 1) << 2);
    }
    const int hword = b_ep * 128 + q * 4 + wave;
    float cst = 0.f;
    const float* gp0 = gx + (size_t)b_ep * 2048 + gx_col;
    float gx0 = gp0[0], gx1 = gp0[512], gx2 = gp0[1024], gx3 = gp0[1536];
    for (int t = 0; t < 256; t++) {
      int buf = t & 1;
      if (t > 0) {
        const unsigned long long* src = hg + (size_t)(t - 1) * 1024;
        unsigned long long v[4];
#pragma unroll
        for (int r = 0; r < 4; r++) v[r] = AL64(src + wi[r]);
        bool redo = true;
        bool first = true;
        while (redo) {
          redo = false;
#pragma unroll
          for (int r = 0; r < 4; r++)
            if (v[r] == SENT) { v[r] = AL64(src + wi[r]); redo = true; }
          if (redo && !first) __builtin_amdgcn_s_sleep(1);  // storm cap; fast path untouched
          first = false;
        }
#pragma unroll
        for (int r = 0; r < 4; r++) *(unsigned long long*)&hb[buf * 8192 + offs[r]] = v[r];
      }
      __syncthreads();  // h ready; all waves' t-1 stores drained (vmcnt0 at barrier)
      if (tid == 0 && t > 0)
        __hip_atomic_fetch_add(prog + (t - 1), 1, __ATOMIC_RELAXED, __HIP_MEMORY_SCOPE_AGENT);
      int tn = (t + 1) & 255;
      const float* gpn = gx + ((size_t)tn * 8 + b_ep) * 2048 + gx_col;
      float n0 = gpn[0], n1 = gpn[512], n2 = gpn[1024], n3 = gpn[1536];
      f32x4 a0 = {}, a1 = {}, a2 = {}, a3 = {};
#pragma unroll
      for (int c = 0; c < 16; c += 4) {
        a0 = mfma16(Af[c + 0], ld8(&hb[buf * 8192 + (((c + 0) * 4 + quad) * 16 + l16) * 8]), a0);
        a1 = mfma16(Af[c + 1], ld8(&hb[buf * 8192 + (((c + 1) * 4 + quad) * 16 + l16) * 8]), a1);
        a2 = mfma16(Af[c + 2], ld8(&hb[buf * 8192 + (((c + 2) * 4 + quad) * 16 + l16) * 8]), a2);
        a3 = mfma16(Af[c + 3], ld8(&hb[buf * 8192 + (((c + 3) * 4 + quad) * 16 + l16) * 8]), a3);
      }
      f32x4 acc = (a0 + a1) + (a2 + a3);
      float gi = acc[0] + gx0, gf = acc[1] + gx1, gg = acc[2] + gx2, go = acc[3] + gx3;
      cst = fsigm(gf) * cst + fsigm(gi) * ftanh(gg);
      float h = fsigm(go) * ftanh(cst);
      unsigned hu = (unsigned short)f2sh(h);
      unsigned h1 = __shfl_xor((int)hu, 16);
      unsigned h2 = __shfl_xor((int)hu, 32);
      unsigned h3 = __shfl_xor((int)h1, 32);
      if (quad == 0 && l16 < 8) {
        unsigned long long w64 = (unsigned long long)hu | ((unsigned long long)h1 << 16) |
                                 ((unsigned long long)h2 << 32) | ((unsigned long long)h3 << 48);
        AS64(hg + (size_t)t * 1024 + hword, w64);
      }
      gx0 = n0; gx1 = n1; gx2 = n2; gx3 = n3;
    }
    __syncthreads();  // drain t=255 stores
    if (tid == 0)
      __hip_atomic_fetch_add(prog + 255, 1, __ATOMIC_RELAXED, __HIP_MEMORY_SCOPE_AGENT);
    return;
  }

  // ================= OUT role (block handles t = bid-40, then +216) =================
  if (tid < 176) ob2s[tid] = ob2p[tid];
  for (int t = bid - 40; t < 256; t += 216) {
    // throttle: one lane spins on ONE word until all 32 lstm blocks published t
    if (tid == 0) {
      while (AL32(prog + t) < 32) __builtin_amdgcn_s_sleep(32);
    }
    __syncthreads();
    // one-shot sentinel-verified read of hg(t) into A-fragments (batch rows; 8..15 zero)
    bf16x8 af[16];
    {
      unsigned long long v[32];
      if (l16 < 8) {
        const unsigned long long* src = hg + (size_t)t * 1024 + l16 * 128;
#pragma unroll
        for (int i = 0; i < 32; i++)
          v[i] = AL64(src + (i >> 1) * 8 + quad * 2 + (i & 1));
        bool redo = true;
        while (redo) {  // prog hint means this almost never retries
          redo = false;
#pragma unroll
          for (int i = 0; i < 32; i++)
            if (v[i] == SENT) { v[i] = AL64(src + (i >> 1) * 8 + quad * 2 + (i & 1)); redo = true; }
          if (redo) __builtin_amdgcn_s_sleep(4);
        }
      } else {
#pragma unroll
        for (int i = 0; i < 32; i++) v[i] = 0ULL;
      }
#pragma unroll
      for (int c = 0; c < 16; c++) af[c] = frag2(v[2*c], v[2*c + 1]);
    }
    // hterm tile: H(t) (8x512) @ ow0M^T -> ht2[8][256]
    {
      f32x4 acch[4] = {};
#pragma unroll
      for (int c = 0; c < 16; c++) {
#pragma unroll
        for (int nt = 0; nt < 4; nt++) {
          bf16x8 wf = ld8(ow0Mb + (size_t)(wave * 64 + nt * 16 + l16) * 512 + c * 32 + quad * 8);
          acch[nt] = mfma16(af[c], wf, acch[nt]);
        }
      }
      if (quad < 2) {
#pragma unroll
        for (int nt = 0; nt < 4; nt++)
#pragma unroll
          for (int r = 0; r < 4; r++)
            ht2[(quad * 4 + r) * 256 + wave * 64 + nt * 16 + l16] = acch[nt][r];
      }
    }
    __syncthreads();
    for (int b = 0; b < 8; b++) {
      if (tid < 80) xt[tid] = mels[((size_t)b * 80 + tid) * 256 + t];
      const bf16* bb = baseb + (size_t)b * 128 * 256;
      {
        int r0 = tid >> 5, c0 = (tid & 31) * 8;
        float hv[8];
#pragma unroll
        for (int j = 0; j < 8; j++) hv[j] = ht2[b * 256 + c0 + j];
        for (int i = r0; i < 128; i += 8) {
          bf16x8 bv = ld8(bb + i * 256 + c0);
          bf16x8 ov;
#pragma unroll
          for (int j = 0; j < 8; j++) {
            float v = sh2f(bv[j]) + hv[j];
            ov[j] = f2sh(v > 0.f ? v : 0.f);
          }
          *(bf16x8*)&a_buf[i * LDA1 + c0] = ov;
        }
      }
      __syncthreads();
      f32x4 accB[8][4] = {};
      for (int kt = 0; kt < 256; kt += 32) {
        bf16x8 wf[4];
#pragma unroll
        for (int nt = 0; nt < 4; nt++)
          wf[nt] = ld8(w1 + (size_t)(wave * 64 + nt * 16 + l16) * 256 + kt + quad * 8);
#pragma unroll
        for (int mt = 0; mt < 8; mt++) {
          bf16x8 afr = ld8(a_buf + (mt * 16 + l16) * LDA1 + kt + quad * 8);
#pragma unroll
          for (int nt = 0; nt < 4; nt++) accB[mt][nt] = mfma16(afr, wf[nt], accB[mt][nt]);
        }
      }
      __syncthreads();
#pragma unroll
      for (int nt = 0; nt < 4; nt++) {
        int col = wave * 64 + nt * 16 + l16;
        float bv = ob1[col];
#pragma unroll
        for (int mt = 0; mt < 8; mt++)
#pragma unroll
          for (int r = 0; r < 4; r++) {
            int row = mt * 16 + quad * 4 + r;
            float v = accB[mt][nt][r] + bv;
            a_buf[row * LDA1 + col] = f2b(v > 0.f ? v : 0.f);
          }
      }
      __syncthreads();
      f32x4 accC[2][11] = {};
      for (int kt = 0; kt < 256; kt += 32) {
        bf16x8 af0 = ld8(a_buf + ((wave * 2 + 0) * 16 + l16) * LDA1 + kt + quad * 8);
        bf16x8 af1 = ld8(a_buf + ((wave * 2 + 1) * 16 + l16) * LDA1 + kt + quad * 8);
#pragma unroll
        for (int nt = 0; nt < 11; nt++) {
          bf16x8 wf = ld8(w2 + (size_t)(nt * 16 + l16) * 256 + kt + quad * 8);
          accC[0][nt] = mfma16(af0, wf, accC[0][nt]);
          accC[1][nt] = mfma16(af1, wf, accC[1][nt]);
        }
      }
      int my_len = ilen[b];
      float xd[5];
#pragma unroll
      for (int qq = 0; qq < 5; qq++) xd[qq] = xt[qq * 16 + l16];
#pragma unroll
      for (int m2 = 0; m2 < 2; m2++)
#pragma unroll
        for (int r = 0; r < 4; r++) {
          int row = (wave * 2 + m2) * 16 + quad * 4 + r;
          float pv[11];
#pragma unroll
          for (int nt = 0; nt < 11; nt++) pv[nt] = accC[m2][nt][r] + ob2s[nt * 16 + l16];
          float s = 0.f;
#pragma unroll
          for (int qq = 0; qq < 5; qq++) {
            float mean = pv[qq], sh = pv[qq + 5];
            float sp = fmaxf(sh, 0.f) + __logf(1.f + __expf(-fabsf(sh)));
            float sd = sp + 0.001f;
            float z = (xd[qq] - mean) / sd;
            s += -0.5f * z * z - __logf(sd);
          }
          s += __shfl_xor(s, 1); s += __shfl_xor(s, 2);
          s += __shfl_xor(s, 4); s += __shfl_xor(s, 8);
          float emv = (row < my_len) ? (s - 80.f * HL2PI) : 0.f;
          if (l16 == 0) {
            size_t oidx = ((size_t)t * 8 + b) * 128 + row;
            AS32(emi + oidx, __float_as_int(emv));
            AS32(tvi + oidx, __float_as_int(pv[10]));
          }
        }
      __syncthreads();
    }
  }
}

// ---------------------------------------------------------------- launch
extern "C" void kernel_launch(void* const* d_in, const int* in_sizes, int n_in,
                              void* d_out, int out_size, void* d_ws, size_t ws_size,
                              hipStream_t stream) {
  const float* inputs = (const float*)d_in[0];
  const float* mels   = (const float*)d_in[1];
  const float* pw0    = (const float*)d_in[2];
  const float* pw1    = (const float*)d_in[3];
  const float* wih    = (const float*)d_in[4];
  const float* whh    = (const float*)d_in[5];
  const float* bih    = (const float*)d_in[6];
  const float* bhh    = (const float*)d_in[7];
  const float* ow0    = (const float*)d_in[8];
  const float* ob0    = (const float*)d_in[9];
  const float* ow1    = (const float*)d_in[10];
  const float* ob1    = (const float*)d_in[11];
  const float* ow2    = (const float*)d_in[12];
  const float* ob2    = (const float*)d_in[13];
  const int* ilen     = (const int*)d_in[14];
  const int* mlen     = (const int*)d_in[15];
  float* out = (float*)d_out;

  char* w = (char*)d_ws;
  size_t off = 0;
  auto carve = [&](size_t bytes) -> char* {
    char* p = w + off;
    off = (off + bytes + 255) & ~(size_t)255;
    return p;
  };
  bf16*  ib     = (bf16*)carve(8*128*512 * 2);
  bf16*  ar     = (bf16*)carve(2048*96 * 2);
  bf16*  w0p    = (bf16*)carve(256*96 * 2);
  bf16*  w1b    = (bf16*)carve(256*256 * 2);
  bf16*  wihb   = (bf16*)carve(2048*256 * 2);
  bf16*  whhb   = (bf16*)carve((size_t)2048*512 * 2);
  float* bias2  = (float*)carve(2048 * 4);
  bf16*  ow0Eb  = (bf16*)carve(256*512 * 2);
  bf16*  ow0Mb  = (bf16*)carve(256*512 * 2);
  bf16*  ow1b   = (bf16*)carve(256*256 * 2);
  bf16*  ow2pb  = (bf16*)carve(176*256 * 2);
  float* ob2p   = (float*)carve(176 * 4);
  bf16*  pre1   = (bf16*)carve(2048*256 * 2);
  bf16*  pre2   = (bf16*)carve(2048*256 * 2);
  float* gx     = (float*)carve((size_t)2048*2048 * 4);
  bf16*  baseb  = (bf16*)carve(1024*256 * 2);
  unsigned long long* hg = (unsigned long long*)carve((size_t)256 * 1024 * 8);
  int*   emi    = (int*)carve((size_t)2048*128 * 4);
  int*   tvi    = (int*)carve((size_t)2048*128 * 4);
  int*   prog   = (int*)carve(256 * 4);

  k_prep<<<512, 256, 0, stream>>>(inputs, mels, pw0, pw1, wih, whh, bih, bhh, ow0, ow1, ow2, ob2,
                                  ib, ar, w0p, w1b, wihb, whhb, bias2, ow0Eb, ow0Mb, ow1b, ow2pb,
                                  ob2p, hg, emi, tvi, prog);
  k_gemm<<<dim3(4, 32), 256, 0, stream>>>(ar, w0p, nullptr, pre1, 2048, 256, 96, 1 | 2);
  k_gemm<<<dim3(4, 32), 256, 0, stream>>>(pre1, w1b, nullptr, pre2, 2048, 256, 256, 1 | 2);
  k_gemm<<<dim3(32, 32), 256, 0, stream>>>(pre2, wihb, bias2, gx, 2048, 2048, 256, 0);
  k_gemm<<<dim3(4, 16), 256, 0, stream>>>(ib, ow0Eb, ob0, baseb, 1024, 256, 512, 2);
  k_mega<<<256, 256, 0, stream>>>(gx, whhb, hg, ow0Mb, baseb, ow1b, ow2pb, ob1, ob2p,
                                  mels, ilen, mlen, emi, tvi, prog, out);
}

// Round 8
// 928.635 us; speedup vs baseline: 1.0584x; 1.0584x over previous
//
#include <hip/hip_runtime.h>
#include <hip/hip_bf16.h>
#include <math.h>

typedef short bf16x8 __attribute__((ext_vector_type(8)));
typedef float f32x4 __attribute__((ext_vector_type(4)));
typedef __hip_bfloat16 bf16;

#define NEGV -1e10f
#define LOGEPS -9.210340371976182f  // log(1e-4)
#define HL2PI 0.9189385332046727f   // 0.5*log(2*pi)
#define SENT 0xFFFFFFFFFFFFFFFFULL

__device__ __forceinline__ f32x4 mfma16(bf16x8 a, bf16x8 b, f32x4 c) {
  return __builtin_amdgcn_mfma_f32_16x16x32_bf16(a, b, c, 0, 0, 0);
}
__device__ __forceinline__ bf16x8 ld8(const bf16* p) { return *(const bf16x8*)(const void*)p; }
__device__ __forceinline__ bf16 f2b(float v) { return __float2bfloat16(v); }
__device__ __forceinline__ float sh2f(short s) {
  unsigned u = ((unsigned)(unsigned short)s) << 16; float f; __builtin_memcpy(&f, &u, 4); return f;
}
__device__ __forceinline__ short f2sh(float v) {
  bf16 b = f2b(v); short s; __builtin_memcpy(&s, &b, 2); return s;
}
__device__ __forceinline__ float fsigm(float x) { return 1.f / (1.f + __expf(-x)); }
__device__ __forceinline__ float ftanh(float x) { return 1.f - 2.f / (1.f + __expf(2.f * x)); }
__device__ __forceinline__ unsigned long long AL64(const unsigned long long* p) {
  return __hip_atomic_load(p, __ATOMIC_RELAXED, __HIP_MEMORY_SCOPE_AGENT);
}
__device__ __forceinline__ void AS64(unsigned long long* p, unsigned long long v) {
  __hip_atomic_store(p, v, __ATOMIC_RELAXED, __HIP_MEMORY_SCOPE_AGENT);
}
__device__ __forceinline__ int AL32(const int* p) {
  return __hip_atomic_load(p, __ATOMIC_RELAXED, __HIP_MEMORY_SCOPE_AGENT);
}
__device__ __forceinline__ void AS32(int* p, int v) {
  __hip_atomic_store(p, v, __ATOMIC_RELAXED, __HIP_MEMORY_SCOPE_AGENT);
}
__device__ __forceinline__ bf16x8 frag2(unsigned long long a, unsigned long long b) {
  union { unsigned long long u[2]; bf16x8 f; } cv; cv.u[0] = a; cv.u[1] = b; return cv.f;
}

// ---------------------------------------------------------------- prep
__global__ void k_prep(const float* __restrict__ inputs, const float* __restrict__ mels,
                       const float* __restrict__ pw0, const float* __restrict__ pw1,
                       const float* __restrict__ wih, const float* __restrict__ whh,
                       const float* __restrict__ bih, const float* __restrict__ bhh,
                       const float* __restrict__ ow0, const float* __restrict__ ow1,
                       const float* __restrict__ ow2, const float* __restrict__ ob2,
                       bf16* ib, bf16* ar, bf16* w0p, bf16* w1b, bf16* wihb, bf16* whhb,
                       float* bias2, bf16* ow0Eb, bf16* ow0Mb, bf16* ow1b, bf16* ow2pb,
                       float* ob2p, unsigned long long* hg, int* emi, int* tvi, int* pcnt) {
  int t0 = blockIdx.x * blockDim.x + threadIdx.x;
  int nt = gridDim.x * blockDim.x;
  for (int i = t0; i < 256 * 1024; i += nt) hg[i] = SENT;   // data-poll sentinels
  for (int i = t0; i < 2048 * 128; i += nt) { emi[i] = -1; tvi[i] = -1; }
  for (int i = t0; i < 32 * 16; i += nt) pcnt[i] = 0;       // per-block progress slots
  for (int i = t0; i < 8*128*512; i += nt) ib[i] = f2b(inputs[i]);
  for (int i = t0; i < 2048*96; i += nt) {
    int r = i / 96, d = i - r * 96; int t = r >> 3, b = r & 7;
    float v = (d < 80 && t > 0) ? mels[((size_t)b*80 + d)*256 + (t-1)] : 0.f;
    ar[i] = f2b(v);
  }
  for (int i = t0; i < 256*96; i += nt) {
    int j = i / 96, d = i - j * 96;
    w0p[i] = f2b(d < 80 ? pw0[j*80 + d] : 0.f);
  }
  for (int i = t0; i < 256*256; i += nt) w1b[i] = f2b(pw1[i]);
  for (int i = t0; i < 2048*256; i += nt) wihb[i] = f2b(wih[i]);
  for (int i = t0; i < 2048*512; i += nt) whhb[i] = f2b(whh[i]);
  for (int i = t0; i < 2048; i += nt) bias2[i] = bih[i] + bhh[i];
  for (int i = t0; i < 256*512; i += nt) {
    int j = i >> 9, k = i & 511;
    ow0Eb[i] = f2b(ow0[(size_t)j*1024 + k]);
    ow0Mb[i] = f2b(ow0[(size_t)j*1024 + 512 + k]);
  }
  for (int i = t0; i < 256*256; i += nt) ow1b[i] = f2b(ow1[i]);
  for (int i = t0; i < 176*256; i += nt) {
    int r = i >> 8;
    ow2pb[i] = f2b(r < 161 ? ow2[i] : 0.f);
  }
  for (int i = t0; i < 176; i += nt) ob2p[i] = (i < 161) ? ob2[i] : 0.f;
}

// ---------------------------------------------------------------- generic MFMA GEMM (head stages)
__global__ __launch_bounds__(256) void k_gemm(const bf16* __restrict__ A, const bf16* __restrict__ W,
                                              const float* __restrict__ bias, void* __restrict__ Cout,
                                              int M, int N, int K, int flags) {
  int wave = threadIdx.x >> 6, lane = threadIdx.x & 63;
  int l16 = lane & 15, quad = lane >> 4;
  int row0 = blockIdx.y * 64 + wave * 16;
  int col0 = blockIdx.x * 64;
  const bf16* arow = A + (size_t)(row0 + l16) * K + quad * 8;
  f32x4 acc[4] = {};
  for (int kt = 0; kt < K; kt += 32) {
    bf16x8 af = ld8(arow + kt);
#pragma unroll
    for (int nt = 0; nt < 4; nt++) {
      bf16x8 wf = ld8(W + (size_t)(col0 + nt*16 + l16) * K + kt + quad * 8);
      acc[nt] = mfma16(af, wf, acc[nt]);
    }
  }
#pragma unroll
  for (int nt = 0; nt < 4; nt++) {
    int col = col0 + nt * 16 + l16;
    float bv = bias ? bias[col] : 0.f;
#pragma unroll
    for (int r = 0; r < 4; r++) {
      int row = row0 + quad * 4 + r;
      float v = acc[nt][r] + bv;
      if (flags & 1) v = v > 0.f ? v : 0.f;
      if (flags & 2) ((bf16*)Cout)[(size_t)row * N + col] = f2b(v);
      else ((float*)Cout)[(size_t)row * N + col] = v;
    }
  }
}

// ---------------------------------------------------------------- mega kernel v4
// 256 blocks x 256 thr, 1 block/CU by LDS padding (dedicated CUs, all co-resident
// by capacity). R8 change vs R7: prog fetch_add hotspot (32 RMWs/step on ONE word,
// acks serialized at MALL, drained at each block's pre-barrier vmcnt(0) -> paced
// the scan) replaced by per-block progress STORES to 64B-separated slots.
//   [0,8)    hmm-role : per-batch HMM forward, polls em/tv sentinels
//   [8,40)   lstm-role: v4 engine; tid0 stores t to its own pcnt slot
//   [40,256) out-role : wave0 lanes 0..31 ballot-poll the 32 slots, then one-shot
//                       sentinel-verified hg read; hterm MFMA + outnet + emission
#define LDA1 264
__global__ __launch_bounds__(256, 1) void k_mega(
    const float* __restrict__ gx, const bf16* __restrict__ whhb,
    unsigned long long* __restrict__ hg, const bf16* __restrict__ ow0Mb,
    const bf16* __restrict__ baseb, const bf16* __restrict__ w1,
    const bf16* __restrict__ w2, const float* __restrict__ ob1,
    const float* __restrict__ ob2p, const float* __restrict__ mels,
    const int* __restrict__ ilen, const int* __restrict__ mlen,
    int* __restrict__ emi, int* __restrict__ tvi, int* __restrict__ pcnt,
    float* __restrict__ out) {
  // 128*264*2 + 4096*2 = 75776 B; + ht2 8192 + xt 320 + ob2s 704 = 84992 B > 81920
  __shared__ __align__(16) bf16 a_buf[128 * LDA1 + 4096];
  __shared__ float ht2[8 * 256];
  __shared__ float xt[80];
  __shared__ float ob2s[176];
  const int bid = blockIdx.x, tid = threadIdx.x;
  const int wave = tid >> 6, lane = tid & 63, l16 = lane & 15, quad = lane >> 4;
  if (tid == 0) a_buf[128 * LDA1 + (bid & 4095)] = f2b(0.f);  // keep pad alive

  if (bid < 8) {  // ================= HMM role =================
    if (tid >= 64) return;
    const int b = bid, ln = tid;
    const int len = ilen[b], ml = mlen[b];
    const bool m0 = ln < len, m1 = (64 + ln) < len;
    float la0 = 0.f, la1 = 0.f, lp = 0.f;
    for (int t = 0; t < 256; t++) {
      const size_t idx = (size_t)t * 1024 + b * 128 + ln;
      int ia0 = AL32(emi + idx), ia1 = AL32(emi + idx + 64);
      int ib0 = AL32(tvi + idx), ib1 = AL32(tvi + idx + 64);
      while (ia0 == -1 || ia1 == -1 || ib0 == -1 || ib1 == -1) {
        __builtin_amdgcn_s_sleep(8);
        if (ia0 == -1) ia0 = AL32(emi + idx);
        if (ia1 == -1) ia1 = AL32(emi + idx + 64);
        if (ib0 == -1) ib0 = AL32(tvi + idx);
        if (ib1 == -1) ib1 = AL32(tvi + idx + 64);
      }
      float e0 = __int_as_float(ia0), e1 = __int_as_float(ia1);
      float v0 = __int_as_float(ib0), v1 = __int_as_float(ib1);
      if (t == 0) {
        la0 = (ln == 0 ? 0.f : NEGV) + e0;
        la1 = NEGV + e1;
      } else {
        float L0 = __logf(1.f + __expf(-fabsf(v0))), L1 = __logf(1.f + __expf(-fabsf(v1)));
        float ls0 = fmaxf(-(fmaxf(v0, 0.f) + L0), LOGEPS);
        float lm0 = fmaxf(-(fmaxf(-v0, 0.f) + L0), LOGEPS);
        float ls1 = fmaxf(-(fmaxf(v1, 0.f) + L1), LOGEPS);
        float lm1 = fmaxf(-(fmaxf(-v1, 0.f) + L1), LOGEPS);
        float stay0 = la0 + ls0, stay1 = la1 + ls1;
        float mv0 = la0 + lm0, mv1 = la1 + lm1;
        float pm0 = __shfl_up(mv0, 1);
        float pm1 = __shfl_up(mv1, 1);
        float mv0_63 = __shfl(mv0, 63);
        float le0 = (ln == 0) ? NEGV : pm0;
        float le1 = (ln == 0) ? mv0_63 : pm1;
        float mxa = fmaxf(stay0, le0), mna = fminf(stay0, le0);
        float o0 = mxa + __logf(1.f + __expf(mna - mxa));
        float mxb = fmaxf(stay1, le1), mnb = fminf(stay1, le1);
        float o1 = mxb + __logf(1.f + __expf(mnb - mxb));
        o0 = m0 ? o0 : NEGV; o1 = m1 ? o1 : NEGV;
        la0 = e0 + o0; la1 = e1 + o1;
      }
      float mx = fmaxf(la0, la1);
#pragma unroll
      for (int s = 1; s < 64; s <<= 1) mx = fmaxf(mx, __shfl_xor(mx, s));
      float sm = __expf(la0 - mx) + __expf(la1 - mx);
#pragma unroll
      for (int s = 1; s < 64; s <<= 1) sm += __shfl_xor(sm, s);
      float lc = mx + __logf(sm);
      la0 -= lc; la1 -= lc;
      size_t o = 8 + ((size_t)b * 256 + t) * 128 + ln;
      out[o] = la0;
      out[o + 64] = la1;
      if (t < ml) lp += lc;
    }
    if (ln == 0) out[b] = lp;
    return;
  }

  if (bid < 40) {  // ================= LSTM role (32 blocks x 4 waves, private CUs) =================
    bf16* hb = a_buf;  // alias: [2][8192] bf16, fragment-order [c4][batch16][8]
    const int q = bid - 8;  // 0..31, owns units q*16 .. q*16+15
    const int jrow = (l16 & 3) * 512 + q * 16 + wave * 4 + (l16 >> 2);
    bf16x8 Af[16];
#pragma unroll
    for (int c = 0; c < 16; c++) Af[c] = ld8(whhb + (size_t)jrow * 512 + c * 32 + quad * 8);
    {
      bf16 z = f2b(0.f);
      for (int i = tid; i < 2 * 8192; i += 256) hb[i] = z;
    }
    const int b_ep = l16 & 7;
    const int gx_col = q * 16 + wave * 4 + quad;
    int wi[4], offs[4];
#pragma unroll
    for (int r = 0; r < 4; r++) {
      wi[r] = tid + 256 * r;
      offs[r] = (((wi[r] & 127) >> 1) * 16 + (wi[r] >> 7)) * 8 + ((wi[r] & 1) << 2);
    }
    const int hword = b_ep * 128 + q * 4 + wave;
    float cst = 0.f;
    const float* gp0 = gx + (size_t)b_ep * 2048 + gx_col;
    float gx0 = gp0[0], gx1 = gp0[512], gx2 = gp0[1024], gx3 = gp0[1536];
    for (int t = 0; t < 256; t++) {
      int buf = t & 1;
      if (t > 0) {
        const unsigned long long* src = hg + (size_t)(t - 1) * 1024;
        unsigned long long v[4];
#pragma unroll
        for (int r = 0; r < 4; r++) v[r] = AL64(src + wi[r]);
        bool redo = true;
        bool first = true;
        while (redo) {
          redo = false;
#pragma unroll
          for (int r = 0; r < 4; r++)
            if (v[r] == SENT) { v[r] = AL64(src + wi[r]); redo = true; }
          if (redo && !first) __builtin_amdgcn_s_sleep(1);  // storm cap; fast path untouched
          first = false;
        }
#pragma unroll
        for (int r = 0; r < 4; r++) *(unsigned long long*)&hb[buf * 8192 + offs[r]] = v[r];
      }
      __syncthreads();  // h ready; all waves' t-1 stores drained (vmcnt0 at barrier)
      // progress publish: plain relaxed STORE to this block's own 64B slot (no RMW)
      if (tid == 0 && t > 0) AS32(pcnt + q * 16, t);
      int tn = (t + 1) & 255;
      const float* gpn = gx + ((size_t)tn * 8 + b_ep) * 2048 + gx_col;
      float n0 = gpn[0], n1 = gpn[512], n2 = gpn[1024], n3 = gpn[1536];
      f32x4 a0 = {}, a1 = {}, a2 = {}, a3 = {};
#pragma unroll
      for (int c = 0; c < 16; c += 4) {
        a0 = mfma16(Af[c + 0], ld8(&hb[buf * 8192 + (((c + 0) * 4 + quad) * 16 + l16) * 8]), a0);
        a1 = mfma16(Af[c + 1], ld8(&hb[buf * 8192 + (((c + 1) * 4 + quad) * 16 + l16) * 8]), a1);
        a2 = mfma16(Af[c + 2], ld8(&hb[buf * 8192 + (((c + 2) * 4 + quad) * 16 + l16) * 8]), a2);
        a3 = mfma16(Af[c + 3], ld8(&hb[buf * 8192 + (((c + 3) * 4 + quad) * 16 + l16) * 8]), a3);
      }
      f32x4 acc = (a0 + a1) + (a2 + a3);
      float gi = acc[0] + gx0, gf = acc[1] + gx1, gg = acc[2] + gx2, go = acc[3] + gx3;
      cst = fsigm(gf) * cst + fsigm(gi) * ftanh(gg);
      float h = fsigm(go) * ftanh(cst);
      unsigned hu = (unsigned short)f2sh(h);
      unsigned h1 = __shfl_xor((int)hu, 16);
      unsigned h2 = __shfl_xor((int)hu, 32);
      unsigned h3 = __shfl_xor((int)h1, 32);
      if (quad == 0 && l16 < 8) {
        unsigned long long w64 = (unsigned long long)hu | ((unsigned long long)h1 << 16) |
                                 ((unsigned long long)h2 << 32) | ((unsigned long long)h3 << 48);
        AS64(hg + (size_t)t * 1024 + hword, w64);
      }
      gx0 = n0; gx1 = n1; gx2 = n2; gx3 = n3;
    }
    __syncthreads();  // drain t=255 stores
    if (tid == 0) AS32(pcnt + q * 16, 256);
    return;
  }

  // ================= OUT role (block handles t = bid-40, then +216) =================
  if (tid < 176) ob2s[tid] = ob2p[tid];
  for (int t = bid - 40; t < 256; t += 216) {
    // wait until all 32 lstm blocks have published h(t): lanes 0..31 each poll one slot
    if (tid < 64) {
      bool ok = (lane >= 32);
      while (true) {
        if (!ok) ok = (AL32(pcnt + lane * 16) >= t + 1);
        if (__all(ok ? 1 : 0)) break;
        __builtin_amdgcn_s_sleep(8);
      }
    }
    __syncthreads();
    // one-shot sentinel-verified read of hg(t) into A-fragments (batch rows; 8..15 zero)
    bf16x8 af[16];
    {
      unsigned long long v[32];
      if (l16 < 8) {
        const unsigned long long* src = hg + (size_t)t * 1024 + l16 * 128;
#pragma unroll
        for (int i = 0; i < 32; i++)
          v[i] = AL64(src + (i >> 1) * 8 + quad * 2 + (i & 1));
        bool redo = true;
        while (redo) {  // pcnt wait means this almost never retries
          redo = false;
#pragma unroll
          for (int i = 0; i < 32; i++)
            if (v[i] == SENT) { v[i] = AL64(src + (i >> 1) * 8 + quad * 2 + (i & 1)); redo = true; }
          if (redo) __builtin_amdgcn_s_sleep(4);
        }
      } else {
#pragma unroll
        for (int i = 0; i < 32; i++) v[i] = 0ULL;
      }
#pragma unroll
      for (int c = 0; c < 16; c++) af[c] = frag2(v[2*c], v[2*c + 1]);
    }
    // hterm tile: H(t) (8x512) @ ow0M^T -> ht2[8][256]
    {
      f32x4 acch[4] = {};
#pragma unroll
      for (int c = 0; c < 16; c++) {
#pragma unroll
        for (int nt = 0; nt < 4; nt++) {
          bf16x8 wf = ld8(ow0Mb + (size_t)(wave * 64 + nt * 16 + l16) * 512 + c * 32 + quad * 8);
          acch[nt] = mfma16(af[c], wf, acch[nt]);
        }
      }
      if (quad < 2) {
#pragma unroll
        for (int nt = 0; nt < 4; nt++)
#pragma unroll
          for (int r = 0; r < 4; r++)
            ht2[(quad * 4 + r) * 256 + wave * 64 + nt * 16 + l16] = acch[nt][r];
      }
    }
    __syncthreads();
    for (int b = 0; b < 8; b++) {
      if (tid < 80) xt[tid] = mels[((size_t)b * 80 + tid) * 256 + t];
      const bf16* bb = baseb + (size_t)b * 128 * 256;
      {
        int r0 = tid >> 5, c0 = (tid & 31) * 8;
        float hv[8];
#pragma unroll
        for (int j = 0; j < 8; j++) hv[j] = ht2[b * 256 + c0 + j];
        for (int i = r0; i < 128; i += 8) {
          bf16x8 bv = ld8(bb + i * 256 + c0);
          bf16x8 ov;
#pragma unroll
          for (int j = 0; j < 8; j++) {
            float v = sh2f(bv[j]) + hv[j];
            ov[j] = f2sh(v > 0.f ? v : 0.f);
          }
          *(bf16x8*)&a_buf[i * LDA1 + c0] = ov;
        }
      }
      __syncthreads();
      f32x4 accB[8][4] = {};
      for (int kt = 0; kt < 256; kt += 32) {
        bf16x8 wf[4];
#pragma unroll
        for (int nt = 0; nt < 4; nt++)
          wf[nt] = ld8(w1 + (size_t)(wave * 64 + nt * 16 + l16) * 256 + kt + quad * 8);
#pragma unroll
        for (int mt = 0; mt < 8; mt++) {
          bf16x8 afr = ld8(a_buf + (mt * 16 + l16) * LDA1 + kt + quad * 8);
#pragma unroll
          for (int nt = 0; nt < 4; nt++) accB[mt][nt] = mfma16(afr, wf[nt], accB[mt][nt]);
        }
      }
      __syncthreads();
#pragma unroll
      for (int nt = 0; nt < 4; nt++) {
        int col = wave * 64 + nt * 16 + l16;
        float bv = ob1[col];
#pragma unroll
        for (int mt = 0; mt < 8; mt++)
#pragma unroll
          for (int r = 0; r < 4; r++) {
            int row = mt * 16 + quad * 4 + r;
            float v = accB[mt][nt][r] + bv;
            a_buf[row * LDA1 + col] = f2b(v > 0.f ? v : 0.f);
          }
      }
      __syncthreads();
      f32x4 accC[2][11] = {};
      for (int kt = 0; kt < 256; kt += 32) {
        bf16x8 af0 = ld8(a_buf + ((wave * 2 + 0) * 16 + l16) * LDA1 + kt + quad * 8);
        bf16x8 af1 = ld8(a_buf + ((wave * 2 + 1) * 16 + l16) * LDA1 + kt + quad * 8);
#pragma unroll
        for (int nt = 0; nt < 11; nt++) {
          bf16x8 wf = ld8(w2 + (size_t)(nt * 16 + l16) * 256 + kt + quad * 8);
          accC[0][nt] = mfma16(af0, wf, accC[0][nt]);
          accC[1][nt] = mfma16(af1, wf, accC[1][nt]);
        }
      }
      int my_len = ilen[b];
      float xd[5];
#pragma unroll
      for (int qq = 0; qq < 5; qq++) xd[qq] = xt[qq * 16 + l16];
#pragma unroll
      for (int m2 = 0; m2 < 2; m2++)
#pragma unroll
        for (int r = 0; r < 4; r++) {
          int row = (wave * 2 + m2) * 16 + quad * 4 + r;
          float pv[11];
#pragma unroll
          for (int nt = 0; nt < 11; nt++) pv[nt] = accC[m2][nt][r] + ob2s[nt * 16 + l16];
          float s = 0.f;
#pragma unroll
          for (int qq = 0; qq < 5; qq++) {
            float mean = pv[qq], sh = pv[qq + 5];
            float sp = fmaxf(sh, 0.f) + __logf(1.f + __expf(-fabsf(sh)));
            float sd = sp + 0.001f;
            float z = (xd[qq] - mean) / sd;
            s += -0.5f * z * z - __logf(sd);
          }
          s += __shfl_xor(s, 1); s += __shfl_xor(s, 2);
          s += __shfl_xor(s, 4); s += __shfl_xor(s, 8);
          float emv = (row < my_len) ? (s - 80.f * HL2PI) : 0.f;
          if (l16 == 0) {
            size_t oidx = ((size_t)t * 8 + b) * 128 + row;
            AS32(emi + oidx, __float_as_int(emv));
            AS32(tvi + oidx, __float_as_int(pv[10]));
          }
        }
      __syncthreads();
    }
  }
}

// ---------------------------------------------------------------- launch
extern "C" void kernel_launch(void* const* d_in, const int* in_sizes, int n_in,
                              void* d_out, int out_size, void* d_ws, size_t ws_size,
                              hipStream_t stream) {
  const float* inputs = (const float*)d_in[0];
  const float* mels   = (const float*)d_in[1];
  const float* pw0    = (const float*)d_in[2];
  const float* pw1    = (const float*)d_in[3];
  const float* wih    = (const float*)d_in[4];
  const float* whh    = (const float*)d_in[5];
  const float* bih    = (const float*)d_in[6];
  const float* bhh    = (const float*)d_in[7];
  const float* ow0    = (const float*)d_in[8];
  const float* ob0    = (const float*)d_in[9];
  const float* ow1    = (const float*)d_in[10];
  const float* ob1    = (const float*)d_in[11];
  const float* ow2    = (const float*)d_in[12];
  const float* ob2    = (const float*)d_in[13];
  const int* ilen     = (const int*)d_in[14];
  const int* mlen     = (const int*)d_in[15];
  float* out = (float*)d_out;

  char* w = (char*)d_ws;
  size_t off = 0;
  auto carve = [&](size_t bytes) -> char* {
    char* p = w + off;
    off = (off + bytes + 255) & ~(size_t)255;
    return p;
  };
  bf16*  ib     = (bf16*)carve(8*128*512 * 2);
  bf16*  ar     = (bf16*)carve(2048*96 * 2);
  bf16*  w0p    = (bf16*)carve(256*96 * 2);
  bf16*  w1b    = (bf16*)carve(256*256 * 2);
  bf16*  wihb   = (bf16*)carve(2048*256 * 2);
  bf16*  whhb   = (bf16*)carve((size_t)2048*512 * 2);
  float* bias2  = (float*)carve(2048 * 4);
  bf16*  ow0Eb  = (bf16*)carve(256*512 * 2);
  bf16*  ow0Mb  = (bf16*)carve(256*512 * 2);
  bf16*  ow1b   = (bf16*)carve(256*256 * 2);
  bf16*  ow2pb  = (bf16*)carve(176*256 * 2);
  float* ob2p   = (float*)carve(176 * 4);
  bf16*  pre1   = (bf16*)carve(2048*256 * 2);
  bf16*  pre2   = (bf16*)carve(2048*256 * 2);
  float* gx     = (float*)carve((size_t)2048*2048 * 4);
  bf16*  baseb  = (bf16*)carve(1024*256 * 2);
  unsigned long long* hg = (unsigned long long*)carve((size_t)256 * 1024 * 8);
  int*   emi    = (int*)carve((size_t)2048*128 * 4);
  int*   tvi    = (int*)carve((size_t)2048*128 * 4);
  int*   pcnt   = (int*)carve(32 * 16 * 4);

  k_prep<<<512, 256, 0, stream>>>(inputs, mels, pw0, pw1, wih, whh, bih, bhh, ow0, ow1, ow2, ob2,
                                  ib, ar, w0p, w1b, wihb, whhb, bias2, ow0Eb, ow0Mb, ow1b, ow2pb,
                                  ob2p, hg, emi, tvi, pcnt);
  k_gemm<<<dim3(4, 32), 256, 0, stream>>>(ar, w0p, nullptr, pre1, 2048, 256, 96, 1 | 2);
  k_gemm<<<dim3(4, 32), 256, 0, stream>>>(pre1, w1b, nullptr, pre2, 2048, 256, 256, 1 | 2);
  k_gemm<<<dim3(32, 32), 256, 0, stream>>>(pre2, wihb, bias2, gx, 2048, 2048, 256, 0);
  k_gemm<<<dim3(4, 16), 256, 0, stream>>>(ib, ow0Eb, ob0, baseb, 1024, 256, 512, 2);
  k_mega<<<256, 256, 0, stream>>>(gx, whhb, hg, ow0Mb, baseb, ow1b, ow2pb, ob1, ob2p,
                                  mels, ilen, mlen, emi, tvi, pcnt, out);
}

// Round 9
// 876.197 us; speedup vs baseline: 1.1217x; 1.0598x over previous
//
#include <hip/hip_runtime.h>
#include <hip/hip_bf16.h>
#include <math.h>

typedef short bf16x8 __attribute__((ext_vector_type(8)));
typedef float f32x4 __attribute__((ext_vector_type(4)));
typedef __hip_bfloat16 bf16;

#define NEGV -1e10f
#define LOGEPS -9.210340371976182f  // log(1e-4)
#define HL2PI 0.9189385332046727f   // 0.5*log(2*pi)
#define SENT 0xFFFFFFFFFFFFFFFFULL

__device__ __forceinline__ f32x4 mfma16(bf16x8 a, bf16x8 b, f32x4 c) {
  return __builtin_amdgcn_mfma_f32_16x16x32_bf16(a, b, c, 0, 0, 0);
}
__device__ __forceinline__ bf16x8 ld8(const bf16* p) { return *(const bf16x8*)(const void*)p; }
__device__ __forceinline__ bf16 f2b(float v) { return __float2bfloat16(v); }
__device__ __forceinline__ float sh2f(short s) {
  unsigned u = ((unsigned)(unsigned short)s) << 16; float f; __builtin_memcpy(&f, &u, 4); return f;
}
__device__ __forceinline__ short f2sh(float v) {
  bf16 b = f2b(v); short s; __builtin_memcpy(&s, &b, 2); return s;
}
__device__ __forceinline__ float fsigm(float x) { return 1.f / (1.f + __expf(-x)); }
__device__ __forceinline__ float ftanh(float x) { return 1.f - 2.f / (1.f + __expf(2.f * x)); }
__device__ __forceinline__ unsigned long long AL64(const unsigned long long* p) {
  return __hip_atomic_load(p, __ATOMIC_RELAXED, __HIP_MEMORY_SCOPE_AGENT);
}
__device__ __forceinline__ void AS64(unsigned long long* p, unsigned long long v) {
  __hip_atomic_store(p, v, __ATOMIC_RELAXED, __HIP_MEMORY_SCOPE_AGENT);
}
__device__ __forceinline__ int AL32(const int* p) {
  return __hip_atomic_load(p, __ATOMIC_RELAXED, __HIP_MEMORY_SCOPE_AGENT);
}
__device__ __forceinline__ void AS32(int* p, int v) {
  __hip_atomic_store(p, v, __ATOMIC_RELAXED, __HIP_MEMORY_SCOPE_AGENT);
}
__device__ __forceinline__ bf16x8 frag2(unsigned long long a, unsigned long long b) {
  union { unsigned long long u[2]; bf16x8 f; } cv; cv.u[0] = a; cv.u[1] = b; return cv.f;
}

// ---------------------------------------------------------------- prep
__global__ void k_prep(const float* __restrict__ inputs, const float* __restrict__ mels,
                       const float* __restrict__ pw0, const float* __restrict__ pw1,
                       const float* __restrict__ wih, const float* __restrict__ whh,
                       const float* __restrict__ bih, const float* __restrict__ bhh,
                       const float* __restrict__ ow0, const float* __restrict__ ow1,
                       const float* __restrict__ ow2, const float* __restrict__ ob2,
                       bf16* ib, bf16* ar, bf16* w0p, bf16* w1b, bf16* wihb, bf16* whhb,
                       float* bias2, bf16* ow0Eb, bf16* ow0Mb, bf16* ow1b, bf16* ow2pb,
                       float* ob2p, unsigned long long* hg, int* emi, int* tvi, int* pcnt) {
  int t0 = blockIdx.x * blockDim.x + threadIdx.x;
  int nt = gridDim.x * blockDim.x;
  for (int i = t0; i < 256 * 1024; i += nt) hg[i] = SENT;   // data-poll sentinels
  for (int i = t0; i < 2048 * 128; i += nt) { emi[i] = -1; tvi[i] = -1; }
  for (int i = t0; i < 32 * 16; i += nt) pcnt[i] = 0;       // per-block progress slots
  for (int i = t0; i < 8*128*512; i += nt) ib[i] = f2b(inputs[i]);
  for (int i = t0; i < 2048*96; i += nt) {
    int r = i / 96, d = i - r * 96; int t = r >> 3, b = r & 7;
    float v = (d < 80 && t > 0) ? mels[((size_t)b*80 + d)*256 + (t-1)] : 0.f;
    ar[i] = f2b(v);
  }
  for (int i = t0; i < 256*96; i += nt) {
    int j = i / 96, d = i - j * 96;
    w0p[i] = f2b(d < 80 ? pw0[j*80 + d] : 0.f);
  }
  for (int i = t0; i < 256*256; i += nt) w1b[i] = f2b(pw1[i]);
  for (int i = t0; i < 2048*256; i += nt) wihb[i] = f2b(wih[i]);
  for (int i = t0; i < 2048*512; i += nt) whhb[i] = f2b(whh[i]);
  for (int i = t0; i < 2048; i += nt) bias2[i] = bih[i] + bhh[i];
  for (int i = t0; i < 256*512; i += nt) {
    int j = i >> 9, k = i & 511;
    ow0Eb[i] = f2b(ow0[(size_t)j*1024 + k]);
    ow0Mb[i] = f2b(ow0[(size_t)j*1024 + 512 + k]);
  }
  for (int i = t0; i < 256*256; i += nt) ow1b[i] = f2b(ow1[i]);
  for (int i = t0; i < 176*256; i += nt) {
    int r = i >> 8;
    ow2pb[i] = f2b(r < 161 ? ow2[i] : 0.f);
  }
  for (int i = t0; i < 176; i += nt) ob2p[i] = (i < 161) ? ob2[i] : 0.f;
}

// ---------------------------------------------------------------- generic MFMA GEMM (head stages)
__global__ __launch_bounds__(256) void k_gemm(const bf16* __restrict__ A, const bf16* __restrict__ W,
                                              const float* __restrict__ bias, void* __restrict__ Cout,
                                              int M, int N, int K, int flags) {
  int wave = threadIdx.x >> 6, lane = threadIdx.x & 63;
  int l16 = lane & 15, quad = lane >> 4;
  int row0 = blockIdx.y * 64 + wave * 16;
  int col0 = blockIdx.x * 64;
  const bf16* arow = A + (size_t)(row0 + l16) * K + quad * 8;
  f32x4 acc[4] = {};
  for (int kt = 0; kt < K; kt += 32) {
    bf16x8 af = ld8(arow + kt);
#pragma unroll
    for (int nt = 0; nt < 4; nt++) {
      bf16x8 wf = ld8(W + (size_t)(col0 + nt*16 + l16) * K + kt + quad * 8);
      acc[nt] = mfma16(af, wf, acc[nt]);
    }
  }
#pragma unroll
  for (int nt = 0; nt < 4; nt++) {
    int col = col0 + nt * 16 + l16;
    float bv = bias ? bias[col] : 0.f;
#pragma unroll
    for (int r = 0; r < 4; r++) {
      int row = row0 + quad * 4 + r;
      float v = acc[nt][r] + bv;
      if (flags & 1) v = v > 0.f ? v : 0.f;
      if (flags & 2) ((bf16*)Cout)[(size_t)row * N + col] = f2b(v);
      else ((float*)Cout)[(size_t)row * N + col] = v;
    }
  }
}

// ---------------------------------------------------------------- mega kernel v5
// 152 blocks x 512 thr, 1 block/CU by LDS padding -> all co-resident by capacity.
// R9 change: lstm-role reverted to the EXACT R4 engine (16 blocks x 512 thr,
// 2 poll words/thread, tight retry) to deconfound publisher-count/config from
// consumer presence. Out-role reworked for 8 waves, 128 blocks x 2 t's.
//   [0,8)    hmm-role : per-batch HMM forward (tid<64), polls em/tv sentinels
//   [8,24)   lstm-role: R4 engine, 8 waves x 4 units; tid0 stores t to pcnt slot
//   [24,152) out-role : t = bid-24 and t+128; ballot-wait on 16 pcnt slots,
//                       one-shot sentinel-verified hg read, hterm MFMA,
//                       outnet + emission, publish em/tv
#define LDA1 264
__global__ __launch_bounds__(512, 1) void k_mega(
    const float* __restrict__ gx, const bf16* __restrict__ whhb,
    unsigned long long* __restrict__ hg, const bf16* __restrict__ ow0Mb,
    const bf16* __restrict__ baseb, const bf16* __restrict__ w1,
    const bf16* __restrict__ w2, const float* __restrict__ ob1,
    const float* __restrict__ ob2p, const float* __restrict__ mels,
    const int* __restrict__ ilen, const int* __restrict__ mlen,
    int* __restrict__ emi, int* __restrict__ tvi, int* __restrict__ pcnt,
    float* __restrict__ out) {
  // 128*264*2 + 4096*2 = 75776 B; + ht2 8192 + xt 320 + ob2s 704 = 84992 B > 81920
  __shared__ __align__(16) bf16 a_buf[128 * LDA1 + 4096];
  __shared__ float ht2[8 * 256];
  __shared__ float xt[80];
  __shared__ float ob2s[176];
  const int bid = blockIdx.x, tid = threadIdx.x;
  const int wave = tid >> 6, lane = tid & 63, l16 = lane & 15, quad = lane >> 4;
  if (tid == 0) a_buf[128 * LDA1 + (bid & 4095)] = f2b(0.f);  // keep pad alive

  if (bid < 8) {  // ================= HMM role =================
    if (tid >= 64) return;
    const int b = bid, ln = tid;
    const int len = ilen[b], ml = mlen[b];
    const bool m0 = ln < len, m1 = (64 + ln) < len;
    float la0 = 0.f, la1 = 0.f, lp = 0.f;
    for (int t = 0; t < 256; t++) {
      const size_t idx = (size_t)t * 1024 + b * 128 + ln;
      int ia0 = AL32(emi + idx), ia1 = AL32(emi + idx + 64);
      int ib0 = AL32(tvi + idx), ib1 = AL32(tvi + idx + 64);
      while (ia0 == -1 || ia1 == -1 || ib0 == -1 || ib1 == -1) {
        __builtin_amdgcn_s_sleep(8);
        if (ia0 == -1) ia0 = AL32(emi + idx);
        if (ia1 == -1) ia1 = AL32(emi + idx + 64);
        if (ib0 == -1) ib0 = AL32(tvi + idx);
        if (ib1 == -1) ib1 = AL32(tvi + idx + 64);
      }
      float e0 = __int_as_float(ia0), e1 = __int_as_float(ia1);
      float v0 = __int_as_float(ib0), v1 = __int_as_float(ib1);
      if (t == 0) {
        la0 = (ln == 0 ? 0.f : NEGV) + e0;
        la1 = NEGV + e1;
      } else {
        float L0 = __logf(1.f + __expf(-fabsf(v0))), L1 = __logf(1.f + __expf(-fabsf(v1)));
        float ls0 = fmaxf(-(fmaxf(v0, 0.f) + L0), LOGEPS);
        float lm0 = fmaxf(-(fmaxf(-v0, 0.f) + L0), LOGEPS);
        float ls1 = fmaxf(-(fmaxf(v1, 0.f) + L1), LOGEPS);
        float lm1 = fmaxf(-(fmaxf(-v1, 0.f) + L1), LOGEPS);
        float stay0 = la0 + ls0, stay1 = la1 + ls1;
        float mv0 = la0 + lm0, mv1 = la1 + lm1;
        float pm0 = __shfl_up(mv0, 1);
        float pm1 = __shfl_up(mv1, 1);
        float mv0_63 = __shfl(mv0, 63);
        float le0 = (ln == 0) ? NEGV : pm0;
        float le1 = (ln == 0) ? mv0_63 : pm1;
        float mxa = fmaxf(stay0, le0), mna = fminf(stay0, le0);
        float o0 = mxa + __logf(1.f + __expf(mna - mxa));
        float mxb = fmaxf(stay1, le1), mnb = fminf(stay1, le1);
        float o1 = mxb + __logf(1.f + __expf(mnb - mxb));
        o0 = m0 ? o0 : NEGV; o1 = m1 ? o1 : NEGV;
        la0 = e0 + o0; la1 = e1 + o1;
      }
      float mx = fmaxf(la0, la1);
#pragma unroll
      for (int s = 1; s < 64; s <<= 1) mx = fmaxf(mx, __shfl_xor(mx, s));
      float sm = __expf(la0 - mx) + __expf(la1 - mx);
#pragma unroll
      for (int s = 1; s < 64; s <<= 1) sm += __shfl_xor(sm, s);
      float lc = mx + __logf(sm);
      la0 -= lc; la1 -= lc;
      size_t o = 8 + ((size_t)b * 256 + t) * 128 + ln;
      out[o] = la0;
      out[o + 64] = la1;
      if (t < ml) lp += lc;
    }
    if (ln == 0) out[b] = lp;
    return;
  }

  if (bid < 24) {  // ============ LSTM role: EXACT R4 engine (16 blocks x 8 waves) ============
    bf16* hb = a_buf;  // alias: [2][8192] bf16, fragment-order [c4][batch16][8]
    const int q = bid - 8;  // 0..15, owns units q*32 .. q*32+31
    const int jrow = (l16 & 3) * 512 + q * 32 + wave * 4 + (l16 >> 2);
    bf16x8 Af[16];
#pragma unroll
    for (int c = 0; c < 16; c++) Af[c] = ld8(whhb + (size_t)jrow * 512 + c * 32 + quad * 8);
    {
      bf16 z = f2b(0.f);
      for (int i = tid; i < 2 * 8192; i += 512) hb[i] = z;
    }
    const int b_ep = l16 & 7;
    const int gx_col = q * 32 + wave * 4 + quad;
    const int w0i = tid, w1i = tid + 512;  // 2 poll words/thread (R4 config)
    const int o0 = (((w0i & 127) >> 1) * 16 + (w0i >> 7)) * 8 + ((w0i & 1) << 2);
    const int o1 = (((w1i & 127) >> 1) * 16 + (w1i >> 7)) * 8 + ((w1i & 1) << 2);
    const int hword = b_ep * 128 + q * 8 + wave;
    float cst = 0.f;
    const float* gp0 = gx + (size_t)b_ep * 2048 + gx_col;
    float gx0 = gp0[0], gx1 = gp0[512], gx2 = gp0[1024], gx3 = gp0[1536];
    for (int t = 0; t < 256; t++) {
      int buf = t & 1;
      if (t > 0) {
        const unsigned long long* src = hg + (size_t)(t - 1) * 1024;
        unsigned long long v0 = AL64(src + w0i);
        unsigned long long v1 = AL64(src + w1i);
        while (v0 == SENT || v1 == SENT) {   // tight, parallel (R4)
          if (v0 == SENT) v0 = AL64(src + w0i);
          if (v1 == SENT) v1 = AL64(src + w1i);
        }
        *(unsigned long long*)&hb[buf * 8192 + o0] = v0;
        *(unsigned long long*)&hb[buf * 8192 + o1] = v1;
      }
      __syncthreads();  // h ready; all waves' t-1 stores drained (vmcnt0 at barrier)
      if (tid == 0 && t > 0) AS32(pcnt + q * 16, t);  // private slot, plain store
      int tn = (t + 1) & 255;
      const float* gpn = gx + ((size_t)tn * 8 + b_ep) * 2048 + gx_col;
      float n0 = gpn[0], n1 = gpn[512], n2 = gpn[1024], n3 = gpn[1536];
      f32x4 a0 = {}, a1 = {}, a2 = {}, a3 = {};
#pragma unroll
      for (int c = 0; c < 16; c += 4) {
        a0 = mfma16(Af[c + 0], ld8(&hb[buf * 8192 + (((c + 0) * 4 + quad) * 16 + l16) * 8]), a0);
        a1 = mfma16(Af[c + 1], ld8(&hb[buf * 8192 + (((c + 1) * 4 + quad) * 16 + l16) * 8]), a1);
        a2 = mfma16(Af[c + 2], ld8(&hb[buf * 8192 + (((c + 2) * 4 + quad) * 16 + l16) * 8]), a2);
        a3 = mfma16(Af[c + 3], ld8(&hb[buf * 8192 + (((c + 3) * 4 + quad) * 16 + l16) * 8]), a3);
      }
      f32x4 acc = (a0 + a1) + (a2 + a3);
      float gi = acc[0] + gx0, gf = acc[1] + gx1, gg = acc[2] + gx2, go = acc[3] + gx3;
      cst = fsigm(gf) * cst + fsigm(gi) * ftanh(gg);
      float h = fsigm(go) * ftanh(cst);
      unsigned hu = (unsigned short)f2sh(h);
      unsigned h1 = __shfl_xor((int)hu, 16);
      unsigned h2 = __shfl_xor((int)hu, 32);
      unsigned h3 = __shfl_xor((int)h1, 32);
      if (quad == 0 && l16 < 8) {
        unsigned long long w64 = (unsigned long long)hu | ((unsigned long long)h1 << 16) |
                                 ((unsigned long long)h2 << 32) | ((unsigned long long)h3 << 48);
        AS64(hg + (size_t)t * 1024 + hword, w64);
      }
      gx0 = n0; gx1 = n1; gx2 = n2; gx3 = n3;
    }
    __syncthreads();  // drain t=255 stores
    if (tid == 0) AS32(pcnt + q * 16, 256);
    return;
  }

  // ================= OUT role (8 waves; t = bid-24, then +128) =================
  if (tid < 176) ob2s[tid] = ob2p[tid];
  for (int t = bid - 24; t < 256; t += 128) {
    // wait until all 16 lstm blocks have published h(t): lanes 0..15 poll slots
    if (tid < 64) {
      bool ok = (lane >= 16);
      while (true) {
        if (!ok) ok = (AL32(pcnt + lane * 16) >= t + 1);
        if (__all(ok ? 1 : 0)) break;
        __builtin_amdgcn_s_sleep(8);
      }
    }
    __syncthreads();
    // one-shot sentinel-verified read of hg(t) into A-fragments (batch rows; 8..15 zero)
    bf16x8 af[16];
    {
      unsigned long long v[32];
      if (l16 < 8) {
        const unsigned long long* src = hg + (size_t)t * 1024 + l16 * 128;
#pragma unroll
        for (int i = 0; i < 32; i++)
          v[i] = AL64(src + (i >> 1) * 8 + quad * 2 + (i & 1));
        bool redo = true;
        while (redo) {  // pcnt wait means this almost never retries
          redo = false;
#pragma unroll
          for (int i = 0; i < 32; i++)
            if (v[i] == SENT) { v[i] = AL64(src + (i >> 1) * 8 + quad * 2 + (i & 1)); redo = true; }
          if (redo) __builtin_amdgcn_s_sleep(4);
        }
      } else {
#pragma unroll
        for (int i = 0; i < 32; i++) v[i] = 0ULL;
      }
#pragma unroll
      for (int c = 0; c < 16; c++) af[c] = frag2(v[2*c], v[2*c + 1]);
    }
    // hterm tile: H(t) (8x512) @ ow0M^T -> ht2[8][256]; 8 waves x 32 cols
    {
      f32x4 acch[2] = {};
#pragma unroll
      for (int c = 0; c < 16; c++) {
#pragma unroll
        for (int nt = 0; nt < 2; nt++) {
          bf16x8 wf = ld8(ow0Mb + (size_t)(wave * 32 + nt * 16 + l16) * 512 + c * 32 + quad * 8);
          acch[nt] = mfma16(af[c], wf, acch[nt]);
        }
      }
      if (quad < 2) {
#pragma unroll
        for (int nt = 0; nt < 2; nt++)
#pragma unroll
          for (int r = 0; r < 4; r++)
            ht2[(quad * 4 + r) * 256 + wave * 32 + nt * 16 + l16] = acch[nt][r];
      }
    }
    __syncthreads();
    for (int b = 0; b < 8; b++) {
      if (tid < 80) xt[tid] = mels[((size_t)b * 80 + tid) * 256 + t];
      const bf16* bb = baseb + (size_t)b * 128 * 256;
      {
        int r0 = tid >> 5, c0 = (tid & 31) * 8;  // 16 row-groups x 32 col-groups
        float hv[8];
#pragma unroll
        for (int j = 0; j < 8; j++) hv[j] = ht2[b * 256 + c0 + j];
        for (int i = r0; i < 128; i += 16) {
          bf16x8 bv = ld8(bb + i * 256 + c0);
          bf16x8 ov;
#pragma unroll
          for (int j = 0; j < 8; j++) {
            float v = sh2f(bv[j]) + hv[j];
            ov[j] = f2sh(v > 0.f ? v : 0.f);
          }
          *(bf16x8*)&a_buf[i * LDA1 + c0] = ov;
        }
      }
      __syncthreads();
      // stage B: 8 waves x 32 cols, all 128 rows
      f32x4 accB[8][2] = {};
      for (int kt = 0; kt < 256; kt += 32) {
        bf16x8 wf[2];
#pragma unroll
        for (int nt = 0; nt < 2; nt++)
          wf[nt] = ld8(w1 + (size_t)(wave * 32 + nt * 16 + l16) * 256 + kt + quad * 8);
#pragma unroll
        for (int mt = 0; mt < 8; mt++) {
          bf16x8 afr = ld8(a_buf + (mt * 16 + l16) * LDA1 + kt + quad * 8);
#pragma unroll
          for (int nt = 0; nt < 2; nt++) accB[mt][nt] = mfma16(afr, wf[nt], accB[mt][nt]);
        }
      }
      __syncthreads();
#pragma unroll
      for (int nt = 0; nt < 2; nt++) {
        int col = wave * 32 + nt * 16 + l16;
        float bv = ob1[col];
#pragma unroll
        for (int mt = 0; mt < 8; mt++)
#pragma unroll
          for (int r = 0; r < 4; r++) {
            int row = mt * 16 + quad * 4 + r;
            float v = accB[mt][nt][r] + bv;
            a_buf[row * LDA1 + col] = f2b(v > 0.f ? v : 0.f);
          }
      }
      __syncthreads();
      // stage C: wave covers rows wave*16..+16, all 11 col-tiles
      f32x4 accC[11] = {};
      for (int kt = 0; kt < 256; kt += 32) {
        bf16x8 af0 = ld8(a_buf + (wave * 16 + l16) * LDA1 + kt + quad * 8);
#pragma unroll
        for (int nt = 0; nt < 11; nt++) {
          bf16x8 wf = ld8(w2 + (size_t)(nt * 16 + l16) * 256 + kt + quad * 8);
          accC[nt] = mfma16(af0, wf, accC[nt]);
        }
      }
      int my_len = ilen[b];
      float xd[5];
#pragma unroll
      for (int qq = 0; qq < 5; qq++) xd[qq] = xt[qq * 16 + l16];
#pragma unroll
      for (int r = 0; r < 4; r++) {
        int row = wave * 16 + quad * 4 + r;
        float pv[11];
#pragma unroll
        for (int nt = 0; nt < 11; nt++) pv[nt] = accC[nt][r] + ob2s[nt * 16 + l16];
        float s = 0.f;
#pragma unroll
        for (int qq = 0; qq < 5; qq++) {
          float mean = pv[qq], sh = pv[qq + 5];
          float sp = fmaxf(sh, 0.f) + __logf(1.f + __expf(-fabsf(sh)));
          float sd = sp + 0.001f;
          float z = (xd[qq] - mean) / sd;
          s += -0.5f * z * z - __logf(sd);
        }
        s += __shfl_xor(s, 1); s += __shfl_xor(s, 2);
        s += __shfl_xor(s, 4); s += __shfl_xor(s, 8);
        float emv = (row < my_len) ? (s - 80.f * HL2PI) : 0.f;
        if (l16 == 0) {
          size_t oidx = ((size_t)t * 8 + b) * 128 + row;
          AS32(emi + oidx, __float_as_int(emv));
          AS32(tvi + oidx, __float_as_int(pv[10]));
        }
      }
      __syncthreads();
    }
  }
}

// ---------------------------------------------------------------- launch
extern "C" void kernel_launch(void* const* d_in, const int* in_sizes, int n_in,
                              void* d_out, int out_size, void* d_ws, size_t ws_size,
                              hipStream_t stream) {
  const float* inputs = (const float*)d_in[0];
  const float* mels   = (const float*)d_in[1];
  const float* pw0    = (const float*)d_in[2];
  const float* pw1    = (const float*)d_in[3];
  const float* wih    = (const float*)d_in[4];
  const float* whh    = (const float*)d_in[5];
  const float* bih    = (const float*)d_in[6];
  const float* bhh    = (const float*)d_in[7];
  const float* ow0    = (const float*)d_in[8];
  const float* ob0    = (const float*)d_in[9];
  const float* ow1    = (const float*)d_in[10];
  const float* ob1    = (const float*)d_in[11];
  const float* ow2    = (const float*)d_in[12];
  const float* ob2    = (const float*)d_in[13];
  const int* ilen     = (const int*)d_in[14];
  const int* mlen     = (const int*)d_in[15];
  float* out = (float*)d_out;

  char* w = (char*)d_ws;
  size_t off = 0;
  auto carve = [&](size_t bytes) -> char* {
    char* p = w + off;
    off = (off + bytes + 255) & ~(size_t)255;
    return p;
  };
  bf16*  ib     = (bf16*)carve(8*128*512 * 2);
  bf16*  ar     = (bf16*)carve(2048*96 * 2);
  bf16*  w0p    = (bf16*)carve(256*96 * 2);
  bf16*  w1b    = (bf16*)carve(256*256 * 2);
  bf16*  wihb   = (bf16*)carve(2048*256 * 2);
  bf16*  whhb   = (bf16*)carve((size_t)2048*512 * 2);
  float* bias2  = (float*)carve(2048 * 4);
  bf16*  ow0Eb  = (bf16*)carve(256*512 * 2);
  bf16*  ow0Mb  = (bf16*)carve(256*512 * 2);
  bf16*  ow1b   = (bf16*)carve(256*256 * 2);
  bf16*  ow2pb  = (bf16*)carve(176*256 * 2);
  float* ob2p   = (float*)carve(176 * 4);
  bf16*  pre1   = (bf16*)carve(2048*256 * 2);
  bf16*  pre2   = (bf16*)carve(2048*256 * 2);
  float* gx     = (float*)carve((size_t)2048*2048 * 4);
  bf16*  baseb  = (bf16*)carve(1024*256 * 2);
  unsigned long long* hg = (unsigned long long*)carve((size_t)256 * 1024 * 8);
  int*   emi    = (int*)carve((size_t)2048*128 * 4);
  int*   tvi    = (int*)carve((size_t)2048*128 * 4);
  int*   pcnt   = (int*)carve(32 * 16 * 4);

  k_prep<<<512, 256, 0, stream>>>(inputs, mels, pw0, pw1, wih, whh, bih, bhh, ow0, ow1, ow2, ob2,
                                  ib, ar, w0p, w1b, wihb, whhb, bias2, ow0Eb, ow0Mb, ow1b, ow2pb,
                                  ob2p, hg, emi, tvi, pcnt);
  k_gemm<<<dim3(4, 32), 256, 0, stream>>>(ar, w0p, nullptr, pre1, 2048, 256, 96, 1 | 2);
  k_gemm<<<dim3(4, 32), 256, 0, stream>>>(pre1, w1b, nullptr, pre2, 2048, 256, 256, 1 | 2);
  k_gemm<<<dim3(32, 32), 256, 0, stream>>>(pre2, wihb, bias2, gx, 2048, 2048, 256, 0);
  k_gemm<<<dim3(4, 16), 256, 0, stream>>>(ib, ow0Eb, ob0, baseb, 1024, 256, 512, 2);
  k_mega<<<152, 512, 0, stream>>>(gx, whhb, hg, ow0Mb, baseb, ow1b, ow2pb, ob1, ob2p,
                                  mels, ilen, mlen, emi, tvi, pcnt, out);
}